// Round 7
// baseline (437.453 us; speedup 1.0000x reference)
//
#include <hip/hip_runtime.h>

typedef __bf16 bf16;
typedef unsigned int u32;
typedef float f32x4 __attribute__((ext_vector_type(4)));
typedef __bf16 bf16x4 __attribute__((ext_vector_type(4)));
typedef __bf16 bf16x8 __attribute__((ext_vector_type(8)));

#define MFMA(a, b, c) __builtin_amdgcn_mfma_f32_16x16x32_bf16((a), (b), (c), 0, 0, 0)

static constexpr int Bc = 4;      // batch
static constexpr int Sc = 2048;   // seq len
static constexpr int Hc = 16;     // heads
static constexpr int DHc = 64;    // head dim
static constexpr int Dc = 1024;   // model dim
static constexpr int Mc = Bc * Sc; // 8192 rows

// async 16B/lane global->LDS. lp must be wave-uniform; lane i lands at lp+16*i.
__device__ __forceinline__ void load_lds16(const bf16* gp, bf16* lp) {
    __builtin_amdgcn_global_load_lds(
        reinterpret_cast<const __attribute__((address_space(1))) u32*>(
            reinterpret_cast<uintptr_t>(gp)),
        reinterpret_cast<__attribute__((address_space(3))) u32*>(
            static_cast<u32>(reinterpret_cast<uintptr_t>(lp))),
        16, 0, 0);
}

// ---------------------------------------------------------------------------
__global__ void fill_diag(float* out, int n) {
    int i = blockIdx.x * 256 + threadIdx.x;
    if (i < n) out[i] = 1000.0f;
}

// ---------------------------------------------------------------------------
// 4x fused 1024x1024 transpose + fp32->bf16: out[n][k] = (bf16)in[k][n]
// ---------------------------------------------------------------------------
__global__ __launch_bounds__(256) void transpose4(const float* __restrict__ i0,
                                                  const float* __restrict__ i1,
                                                  const float* __restrict__ i2,
                                                  const float* __restrict__ i3,
                                                  bf16* __restrict__ o0,
                                                  bf16* __restrict__ o1,
                                                  bf16* __restrict__ o2,
                                                  bf16* __restrict__ o3) {
    const float* in = (blockIdx.z == 0) ? i0 : (blockIdx.z == 1) ? i1
                     : (blockIdx.z == 2) ? i2 : i3;
    bf16* out = (blockIdx.z == 0) ? o0 : (blockIdx.z == 1) ? o1
               : (blockIdx.z == 2) ? o2 : o3;
    __shared__ bf16 t[32][33];
    int x = blockIdx.x * 32 + threadIdx.x;
#pragma unroll
    for (int j = 0; j < 32; j += 8) {
        int y = blockIdx.y * 32 + threadIdx.y + j;
        t[threadIdx.y + j][threadIdx.x] = (bf16)in[y * 1024 + x];
    }
    __syncthreads();
    int x2 = blockIdx.y * 32 + threadIdx.x;
#pragma unroll
    for (int j = 0; j < 32; j += 8) {
        int y2 = blockIdx.x * 32 + threadIdx.y + j;
        out[y2 * 1024 + x2] = t[threadIdx.x][threadIdx.y + j];
    }
}

// ---------------------------------------------------------------------------
// Fused QKV projection GEMM. grid (8, 64, 3): z selects {query,key,value}.
// C[M,N] = (bf16)A_f32[M,K] @ Wt[N,K]^T + bias[N].
// A: fp32 load + cvt + ds_write_b128 into rows padded to 40 (2-way only = free);
// B: global_load_lds width-16 (m97 pattern). 128x128 tile, BK=32.
// z=0,1 -> out [B,H,S,Dh]; z=2 -> out [B,H,Dh,S].
// ---------------------------------------------------------------------------
static constexpr int AP = 40;  // padded A-row stride in LDS (elements)

__global__ __launch_bounds__(256) void gemm_qkv(
    const float* __restrict__ Aq, const float* __restrict__ Ak,
    const float* __restrict__ Av,
    const bf16* __restrict__ Wq, const bf16* __restrict__ Wk,
    const bf16* __restrict__ Wv,
    const float* __restrict__ bq, const float* __restrict__ bk,
    const float* __restrict__ bv,
    bf16* __restrict__ Qb, bf16* __restrict__ Kb, bf16* __restrict__ Vtb) {
    const int z = blockIdx.z;
    const float* A = (z == 0) ? Aq : (z == 1) ? Ak : Av;
    const bf16* Wt = (z == 0) ? Wq : (z == 1) ? Wk : Wv;
    const float* bias = (z == 0) ? bq : (z == 1) ? bk : bv;
    bf16* out = (z == 0) ? Qb : (z == 1) ? Kb : Vtb;
    const int K = Dc, N = Dc;

    __shared__ alignas(16) bf16 As[128 * AP];
    __shared__ alignas(16) bf16 Bs[128 * 32];
    const int tid = threadIdx.x;
    const int wave = tid >> 6, lane = tid & 63;
    const int quad = lane >> 4, l16 = lane & 15;
    const int wr = (wave >> 1) * 64, wc = (wave & 1) * 64;
    const int row0 = blockIdx.y * 128, col0 = blockIdx.x * 128;

    // B staging: wave covers cols [wave*32, wave*32+32)
    const int sr = wave * 32 + (lane >> 2);
    const int sk = (lane & 3) * 8;
    const bf16* gB = &Wt[(size_t)(col0 + sr) * K + sk];
    bf16* lB = &Bs[wave * 32 * 32];

    f32x4 acc[4][4];
#pragma unroll
    for (int mi = 0; mi < 4; ++mi)
#pragma unroll
        for (int ni = 0; ni < 4; ++ni)
            acc[mi][ni] = (f32x4){0.f, 0.f, 0.f, 0.f};

    for (int k0 = 0; k0 < K; k0 += 32) {
        __syncthreads();
        load_lds16(gB + k0, lB);
        load_lds16(gB + k0 + 16 * K, lB + 16 * 32);
#pragma unroll
        for (int p = 0; p < 2; ++p) {
            int i = p * 256 + tid;
            int r = i >> 2, kb = (i & 3) * 8;
            const float* s = &A[(size_t)(row0 + r) * K + k0 + kb];
            f32x4 x0 = *(const f32x4*)s;
            f32x4 x1 = *(const f32x4*)(s + 4);
            bf16x8 v;
#pragma unroll
            for (int j = 0; j < 4; ++j) { v[j] = (bf16)x0[j]; v[j + 4] = (bf16)x1[j]; }
            *(bf16x8*)&As[r * AP + kb] = v;
        }
        __syncthreads();   // drains vmcnt + lgkmcnt before LDS reads

        bf16x8 af[4], bf_[4];
#pragma unroll
        for (int mi = 0; mi < 4; ++mi)
            af[mi] = *(const bf16x8*)&As[(wr + mi * 16 + l16) * AP + quad * 8];
#pragma unroll
        for (int ni = 0; ni < 4; ++ni)
            bf_[ni] = *(const bf16x8*)&Bs[(wc + ni * 16 + l16) * 32 + quad * 8];
#pragma unroll
        for (int mi = 0; mi < 4; ++mi)
#pragma unroll
            for (int ni = 0; ni < 4; ++ni)
                acc[mi][ni] = MFMA(af[mi], bf_[ni], acc[mi][ni]);
    }

    // epilogue: C/D layout col=lane&15, row=quad*4+reg
#pragma unroll
    for (int mi = 0; mi < 4; ++mi) {
#pragma unroll
        for (int ni = 0; ni < 4; ++ni) {
            int col = col0 + wc + ni * 16 + l16;
            float bv = bias[col];
#pragma unroll
            for (int r = 0; r < 4; ++r) {
                int row = row0 + wr + mi * 16 + quad * 4 + r;
                float v = acc[mi][ni][r] + bv;
                int b = row >> 11, s = row & (Sc - 1);
                int h = col >> 6, dh = col & (DHc - 1);
                size_t off = (z != 2)
                    ? (((size_t)(b * Hc + h) * Sc + s) << 6) + dh
                    : (((size_t)(b * Hc + h) * DHc + dh) << 11) + s;
                out[off] = (bf16)v;
            }
        }
    }
}

// ---------------------------------------------------------------------------
// O-projection GEMM (bf16 A): m97 pattern, both operands via global_load_lds.
// out row-major [M,N] fp32.
// ---------------------------------------------------------------------------
__global__ __launch_bounds__(256) void gemm_o(const bf16* __restrict__ A,
                                              const bf16* __restrict__ Wt,
                                              const float* __restrict__ bias,
                                              float* __restrict__ out,
                                              int M, int N, int K) {
    __shared__ alignas(16) bf16 As[128 * 32];
    __shared__ alignas(16) bf16 Bs[128 * 32];
    const int tid = threadIdx.x;
    const int wave = tid >> 6, lane = tid & 63;
    const int quad = lane >> 4, l16 = lane & 15;
    const int wr = (wave >> 1) * 64, wc = (wave & 1) * 64;
    const int row0 = blockIdx.y * 128, col0 = blockIdx.x * 128;

    const int sr = wave * 32 + (lane >> 2);
    const int sk = (lane & 3) * 8;
    const bf16* gA = &A[(size_t)(row0 + sr) * K + sk];
    const bf16* gB = &Wt[(size_t)(col0 + sr) * K + sk];
    bf16* lA = &As[wave * 32 * 32];
    bf16* lB = &Bs[wave * 32 * 32];

    f32x4 acc[4][4];
#pragma unroll
    for (int mi = 0; mi < 4; ++mi)
#pragma unroll
        for (int ni = 0; ni < 4; ++ni)
            acc[mi][ni] = (f32x4){0.f, 0.f, 0.f, 0.f};

    for (int k0 = 0; k0 < K; k0 += 32) {
        __syncthreads();
        load_lds16(gA + k0, lA);
        load_lds16(gA + k0 + 16 * K, lA + 16 * 32);
        load_lds16(gB + k0, lB);
        load_lds16(gB + k0 + 16 * K, lB + 16 * 32);
        __syncthreads();

        bf16x8 af[4], bf_[4];
#pragma unroll
        for (int mi = 0; mi < 4; ++mi)
            af[mi] = *(const bf16x8*)&As[(wr + mi * 16 + l16) * 32 + quad * 8];
#pragma unroll
        for (int ni = 0; ni < 4; ++ni)
            bf_[ni] = *(const bf16x8*)&Bs[(wc + ni * 16 + l16) * 32 + quad * 8];
#pragma unroll
        for (int mi = 0; mi < 4; ++mi)
#pragma unroll
            for (int ni = 0; ni < 4; ++ni)
                acc[mi][ni] = MFMA(af[mi], bf_[ni], acc[mi][ni]);
    }

#pragma unroll
    for (int mi = 0; mi < 4; ++mi) {
#pragma unroll
        for (int ni = 0; ni < 4; ++ni) {
            int col = col0 + wc + ni * 16 + l16;
            float bv = bias[col];
#pragma unroll
            for (int r = 0; r < 4; ++r) {
                int row = row0 + wr + mi * 16 + quad * 4 + r;
                out[(size_t)row * N + col] = acc[mi][ni][r] + bv;
            }
        }
    }
}

// ---------------------------------------------------------------------------
// Flash-style causal attention (MFMA), v3.1: S^T formulation + exp2 folding.
// v_exp_f32 is natively 2^x: p = exp2(st * (log2e/4096) + mk) with mask
// already in the folded domain -> 1 FMA + 1 exp per element.
// ---------------------------------------------------------------------------
static constexpr int LP = 72; // padded LDS row stride (elements)

__global__ __launch_bounds__(256, 4) void attn_fwd(const bf16* __restrict__ Q,
                                                   const bf16* __restrict__ K,
                                                   const bf16* __restrict__ Vt,
                                                   const int* __restrict__ mask,
                                                   bf16* __restrict__ Ctx) {
    __shared__ alignas(16) bf16 Ks[64 * LP];
    __shared__ alignas(16) bf16 Vs[64 * LP];      // Vs[dh][key]
    __shared__ alignas(16) bf16 Ps[4][32 * LP];   // per-wave P[q][key]
    __shared__ alignas(16) float msk[64];

    const int tid = threadIdx.x;
    const int wave = tid >> 6, lane = tid & 63;
    const int quad = lane >> 4, l16 = lane & 15;
    const int bh = blockIdx.y, b = bh >> 4, h = bh & 15;
    const int qt = gridDim.x - 1 - blockIdx.x;   // heaviest first
    const int q0 = qt * 128;
    const int qr0 = q0 + wave * 32;
    const int qmax = qr0 + 31;
    const float C2 = 1.4426950408889634f / 4096.0f;  // log2(e)/Dh^2

    // Q fragments (B-operand of S^T): n=q=l16, k=dh=quad*8+j ; [mt][chunk]
    bf16x8 bq[2][2];
#pragma unroll
    for (int mt = 0; mt < 2; ++mt) {
        const size_t qoff = ((size_t)bh * Sc + qr0 + mt * 16 + l16) * DHc;
        bq[mt][0] = *(const bf16x8*)&Q[qoff + quad * 8];
        bq[mt][1] = *(const bf16x8*)&Q[qoff + 32 + quad * 8];
    }

    f32x4 accO[2][4];
#pragma unroll
    for (int mt = 0; mt < 2; ++mt)
#pragma unroll
        for (int oi = 0; oi < 4; ++oi) accO[mt][oi] = (f32x4){0.f, 0.f, 0.f, 0.f};
    float l_part[2] = {0.f, 0.f};                // per-lane partial for q=l16

    const int nkt = 2 * qt + 2;                  // causal: k-tiles 0..(2qt+1)
    for (int kt = 0; kt < nkt; ++kt) {
        const int kb = kt * 64;
        __syncthreads();
#pragma unroll
        for (int p = 0; p < 2; ++p) {
            int i = p * 256 + tid;
            int r = i >> 3, c8 = (i & 7) * 8;
            *(uint4*)&Ks[r * LP + c8] =
                *(const uint4*)&K[((size_t)bh * Sc + kb + r) * DHc + c8];
            *(uint4*)&Vs[r * LP + c8] =
                *(const uint4*)&Vt[((size_t)bh * DHc + r) * Sc + kb + c8];
        }
        if (tid < 64)
            msk[tid] = (mask[b * Sc + kb + tid] == 0) ? -1e30f : 0.0f;
        __syncthreads();

        if (kb > qmax) continue;                 // wave-uniform skip

        // S^T = K Q^T : A-frag = K rows (m=key), B-frag = bq (n=q)
        f32x4 st[2][4];
#pragma unroll
        for (int kti = 0; kti < 4; ++kti) {
            bf16x8 ak0 = *(const bf16x8*)&Ks[(kti * 16 + l16) * LP + quad * 8];
            bf16x8 ak1 = *(const bf16x8*)&Ks[(kti * 16 + l16) * LP + 32 + quad * 8];
#pragma unroll
            for (int mt = 0; mt < 2; ++mt) {
                f32x4 z = {0.f, 0.f, 0.f, 0.f};
                z = MFMA(ak0, bq[mt][0], z);
                z = MFMA(ak1, bq[mt][1], z);
                st[mt][kti] = z;
            }
        }

        // softmax numerator (shift=0, exp2 domain); packed P store
#pragma unroll
        for (int mt = 0; mt < 2; ++mt) {
#pragma unroll
            for (int kti = 0; kti < 4; ++kti) {
                const f32x4 mkv = *(const f32x4*)&msk[kti * 16 + quad * 4];
                const int cbase = kb + kti * 16 + quad * 4 - (qr0 + mt * 16);
                bf16x4 pv;
#pragma unroll
                for (int r = 0; r < 4; ++r) {
                    float s = st[mt][kti][r] * C2 + mkv[r];
                    s = (cbase + r > l16) ? -1e30f : s;   // causal: kg > qg
                    float p = __builtin_amdgcn_exp2f(s);
                    l_part[mt] += p;
                    pv[r] = (bf16)p;
                }
                *(bf16x4*)&Ps[wave][(mt * 16 + l16) * LP + kti * 16 + quad * 4] = pv;
            }
        }
        // Ps[wave] is wave-private; per-wave DS ordering suffices (no barrier)

        // O += P V : A = Ps rows (m=q), B = Vs rows (n=dh)
#pragma unroll
        for (int kk = 0; kk < 2; ++kk) {
            bf16x8 ap0 = *(const bf16x8*)&Ps[wave][(l16) * LP + kk * 32 + quad * 8];
            bf16x8 ap1 = *(const bf16x8*)&Ps[wave][(16 + l16) * LP + kk * 32 + quad * 8];
#pragma unroll
            for (int oi = 0; oi < 4; ++oi) {
                bf16x8 bv = *(const bf16x8*)&Vs[(oi * 16 + l16) * LP + kk * 32 + quad * 8];
                accO[0][oi] = MFMA(ap0, bv, accO[0][oi]);
                accO[1][oi] = MFMA(ap1, bv, accO[1][oi]);
            }
        }
    }

    // epilogue: finish l (sum over quads), redistribute to C-layout rows, store
    float lv[2][4];
#pragma unroll
    for (int mt = 0; mt < 2; ++mt) {
        float l = l_part[mt];
        l += __shfl_xor(l, 16);
        l += __shfl_xor(l, 32);                  // lane holds l for q=l16
#pragma unroll
        for (int r = 0; r < 4; ++r)
            lv[mt][r] = __shfl(l, quad * 4 + r); // l for q=quad*4+r
    }
#pragma unroll
    for (int mt = 0; mt < 2; ++mt)
#pragma unroll
        for (int oi = 0; oi < 4; ++oi)
#pragma unroll
            for (int r = 0; r < 4; ++r) {
                int s = qr0 + mt * 16 + quad * 4 + r;
                int dh = oi * 16 + l16;
                float v = accO[mt][oi][r] / lv[mt][r];
                Ctx[((size_t)b * Sc + s) * Dc + h * DHc + dh] = (bf16)v;
            }
}

// ---------------------------------------------------------------------------
extern "C" void kernel_launch(void* const* d_in, const int* in_sizes, int n_in,
                              void* d_out, int out_size, void* d_ws, size_t ws_size,
                              hipStream_t stream) {
    const float* query = (const float*)d_in[0];
    const float* key_i = (const float*)d_in[1];
    const float* value = (const float*)d_in[2];
    const int* mask    = (const int*)d_in[3];
    const float* W_q = (const float*)d_in[4];
    const float* b_q = (const float*)d_in[5];
    const float* W_k = (const float*)d_in[6];
    const float* b_k = (const float*)d_in[7];
    const float* W_v = (const float*)d_in[8];
    const float* b_v = (const float*)d_in[9];
    const float* W_o = (const float*)d_in[10];
    const float* b_o = (const float*)d_in[11];
    float* out = (float*)d_out;

    const size_t MB = 1024 * 1024;
    const size_t NEED = 72 * MB;
    if (ws_size < NEED) {
        fill_diag<<<(out_size + 255) / 256, 256, 0, stream>>>(out, out_size);
        return;
    }

    char* ws = (char*)d_ws;
    bf16* WtQ = (bf16*)(ws + 0 * MB);   // 2 MB each
    bf16* WtK = (bf16*)(ws + 2 * MB);
    bf16* WtV = (bf16*)(ws + 4 * MB);
    bf16* WtO = (bf16*)(ws + 6 * MB);
    bf16* Ctx = (bf16*)(ws + 8 * MB);   // [B,S,D] 16 MB
    bf16* Qb  = (bf16*)(ws + 24 * MB);  // [B,H,S,Dh]
    bf16* Kb  = (bf16*)(ws + 40 * MB);  // [B,H,S,Dh]
    bf16* Vtb = (bf16*)(ws + 56 * MB);  // [B,H,Dh,S]

    transpose4<<<dim3(32, 32, 4), dim3(32, 8), 0, stream>>>(
        W_q, W_k, W_v, W_o, WtQ, WtK, WtV, WtO);

    gemm_qkv<<<dim3(Dc / 128, Mc / 128, 3), 256, 0, stream>>>(
        query, key_i, value, WtQ, WtK, WtV, b_q, b_k, b_v, Qb, Kb, Vtb);

    attn_fwd<<<dim3(Sc / 128, Bc * Hc), 256, 0, stream>>>(Qb, Kb, Vtb, mask, Ctx);

    gemm_o<<<dim3(Dc / 128, Mc / 128), 256, 0, stream>>>(
        Ctx, WtO, b_o, out, Mc, Dc, Dc);
}